// Round 2
// baseline (276.137 us; speedup 1.0000x reference)
//
#include <hip/hip_runtime.h>

// ---------------- problem constants ----------------
#define DIM     384
#define QKV_CH  1152          // 3*DIM
#define HD      32            // head dim
#define CD      128           // channels per dilation group (4 heads)
#define BATCH   4
#define SEQ     8192
#define ROWS    (BATCH*SEQ)   // 32768
#define SCALE   0.17677669529663687f   // 32^-0.5

#define KB8         48            // K/8 for K=384
#define FRAG_STRIDE (KB8*128)     // 6144 shorts per 16-row block in swizzled layout
#define XRB_MAX     (ROWS/16 - 1) // 2047

typedef short bf16x8 __attribute__((ext_vector_type(8)));
typedef float f32x4  __attribute__((ext_vector_type(4)));

__device__ __forceinline__ unsigned short f2bf(float f) {
  unsigned int u = __float_as_uint(f);
  u += 0x7fffu + ((u >> 16) & 1u);      // RNE
  return (unsigned short)(u >> 16);
}
__device__ __forceinline__ float bf2f(unsigned short b) {
  return __uint_as_float(((unsigned int)b) << 16);
}
__device__ __forceinline__ void unpack4(uint2 u, float* f) {
  f[0] = bf2f((unsigned short)(u.x & 0xffffu)); f[1] = bf2f((unsigned short)(u.x >> 16));
  f[2] = bf2f((unsigned short)(u.y & 0xffffu)); f[3] = bf2f((unsigned short)(u.y >> 16));
}

// LDS XOR swizzle for the qkv tiles: row stride 128 shorts (256B). XOR short-
// index bits 2..6 with (row&31) -> 8B-granule permutation within the row.
__device__ __forceinline__ int swz(int row, int col) {   // col multiple of 4
  return (row * 128 + col) ^ ((row & 31) << 2);
}

// ================= global swizzled (fragment-major) layout =================
// swz_g(r,k; K=384) = ((r/16)*48 + k/8)*128 + (r%16)*8 + (k%8)
// MFMA fragment (16 rows x 32 k) = base + lane*8 shorts, one coalesced 1KB wave load.

// ---------------- fp32 -> swizzled bf16 convert (x, Wqkv, Wproj in one launch) ----------------
__global__ __launch_bounds__(256) void cvt_all(const float* __restrict__ x,
                                               const float* __restrict__ wqkv,
                                               const float* __restrict__ wproj,
                                               unsigned short* __restrict__ xo,
                                               unsigned short* __restrict__ qo,
                                               unsigned short* __restrict__ po) {
  int cid = blockIdx.x * 256 + threadIdx.x;
  const float* in; unsigned short* out;
  if (cid < 1572864) { in = x; out = xo; }                         // 32768*48 chunks
  else if (cid < 1628160) { cid -= 1572864; in = wqkv; out = qo; } // 1152*48
  else { cid -= 1628160; in = wproj; out = po; }                   // 384*48
  int rl = cid & 15;
  int q  = cid >> 4;
  int rb = q / KB8;
  int kb = q - rb * KB8;
  const float* p = in + (size_t)(rb * 16 + rl) * DIM + kb * 8;
  float4 a = *(const float4*)p;
  float4 b = *(const float4*)(p + 4);
  uint4 u;
  u.x = (unsigned int)f2bf(a.x) | ((unsigned int)f2bf(a.y) << 16);
  u.y = (unsigned int)f2bf(a.z) | ((unsigned int)f2bf(a.w) << 16);
  u.z = (unsigned int)f2bf(b.x) | ((unsigned int)f2bf(b.y) << 16);
  u.w = (unsigned int)f2bf(b.z) | ((unsigned int)f2bf(b.w) << 16);
  *(uint4*)(out + (size_t)cid * 8) = u;
}

// ---------------- fully fused: QKV proj + dilated attention + out proj ----------------
// Block = 64 rows, 512 threads (8 waves), 1 block/CU (112 KB LDS).
// Loop d=0..2: phase1 MFMA qkv (wave w -> one 16-col block; acc 16 f32x4),
// stage bf16 qkv in swizzled LDS; phase2 pair-split 3-tap softmax-attention,
// write 64x384 attn tile (fragment-major LDS). Then phase3: out = attn @ Wproj^T
// + bproj straight from LDS fragments, fp32 row-major to global.
// __launch_bounds__(512,2): cap 256 regs/wave on the unified VGPR+AGPR file
// (round-1 lesson: (512,4)=128-reg cap forced a catastrophic scratch spill).
__global__ __launch_bounds__(512, 2) void fused_all(
    const unsigned short* __restrict__ X,     // x_swz    [ROWS,384] swizzled
    const unsigned short* __restrict__ W,     // wqkv_swz [1152,384] swizzled
    const float* __restrict__ bqkv,           // [1152]
    const unsigned short* __restrict__ Wp,    // wproj_swz [384,384] swizzled
    const float* __restrict__ bproj,          // [384]
    float* __restrict__ out) {                // [ROWS,384] fp32 row-major
  __shared__ unsigned short sm[57344];        // 114688 B
  unsigned short* q_t = sm;                   // 64 rows x 128 (XOR-swizzled)
  unsigned short* k_t = sm + 64 * 128;        // 96 rows (row0-16 .. row0+80)
  unsigned short* v_t = sm + 160 * 128;       // 96 rows
  unsigned short* a_t = sm + 256 * 128;       // attn tile 64x384, fragment-major

  const int t = threadIdx.x;
  const int w = t >> 6, lane = t & 63;
  const int quad = lane >> 4, l16 = lane & 15;
  const int row0 = blockIdx.x * 64;
  const int rb0 = row0 >> 4;

  // x fragment pointers (shared by all d-groups; all waves read the same ones -> L1 hits)
  const unsigned short* pa[6];
#pragma unroll
  for (int j = 0; j < 6; ++j) {
    int xrb = rb0 - 1 + j;                               // halo row-blocks, clamped
    xrb = xrb < 0 ? 0 : (xrb > XRB_MAX ? XRB_MAX : xrb); // at global edges (masked taps)
    pa[j] = X + (size_t)xrb * FRAG_STRIDE + lane * 8;
  }

#pragma unroll 1
  for (int d = 0; d < 3; ++d) {
    // ---- phase 1: MFMA. wave w -> col-block w (16 cols) of q,k,v; all row-blocks.
    const int wrb = d * 8 + w;                           // weight row-block (channel/16)
    const unsigned short* pbq = W + (size_t)wrb * FRAG_STRIDE + lane * 8;
    const unsigned short* pbk = pbq + (size_t)24 * FRAG_STRIDE;
    const unsigned short* pbv = pbq + (size_t)48 * FRAG_STRIDE;

    f32x4 aq[4] = {}, ak[6] = {}, av[6] = {};

#pragma unroll
    for (int kk = 0; kk < 12; ++kk) {
      bf16x8 a[6];
#pragma unroll
      for (int j = 0; j < 6; ++j) a[j] = *(const bf16x8*)(pa[j] + kk * 512);
      bf16x8 bq = *(const bf16x8*)(pbq + kk * 512);
      bf16x8 bk = *(const bf16x8*)(pbk + kk * 512);
      bf16x8 bv = *(const bf16x8*)(pbv + kk * 512);
#pragma unroll
      for (int j = 0; j < 4; ++j)
        aq[j] = __builtin_amdgcn_mfma_f32_16x16x32_bf16(bq, a[j + 1], aq[j], 0, 0, 0);
#pragma unroll
      for (int j = 0; j < 6; ++j)
        ak[j] = __builtin_amdgcn_mfma_f32_16x16x32_bf16(bk, a[j], ak[j], 0, 0, 0);
#pragma unroll
      for (int j = 0; j < 6; ++j)
        av[j] = __builtin_amdgcn_mfma_f32_16x16x32_bf16(bv, a[j], av[j], 0, 0, 0);
    }

    // ---- epilogue: bias + bf16 + swizzled LDS stage. lane: row l16, cols colb+reg.
    {
      const int colb = w * 16 + quad * 4;
      float4 b_q = *(const float4*)&bqkv[d * CD + colb];
      float4 b_k = *(const float4*)&bqkv[384 + d * CD + colb];
      float4 b_v = *(const float4*)&bqkv[768 + d * CD + colb];
#pragma unroll
      for (int j = 0; j < 4; ++j) {
        uint2 u;
        u.x = (unsigned int)f2bf(aq[j][0] + b_q.x) | ((unsigned int)f2bf(aq[j][1] + b_q.y) << 16);
        u.y = (unsigned int)f2bf(aq[j][2] + b_q.z) | ((unsigned int)f2bf(aq[j][3] + b_q.w) << 16);
        *(uint2*)&q_t[swz(j * 16 + l16, colb)] = u;
      }
#pragma unroll
      for (int j = 0; j < 6; ++j) {
        uint2 u;
        u.x = (unsigned int)f2bf(ak[j][0] + b_k.x) | ((unsigned int)f2bf(ak[j][1] + b_k.y) << 16);
        u.y = (unsigned int)f2bf(ak[j][2] + b_k.z) | ((unsigned int)f2bf(ak[j][3] + b_k.w) << 16);
        *(uint2*)&k_t[swz(j * 16 + l16, colb)] = u;
      }
#pragma unroll
      for (int j = 0; j < 6; ++j) {
        uint2 u;
        u.x = (unsigned int)f2bf(av[j][0] + b_v.x) | ((unsigned int)f2bf(av[j][1] + b_v.y) << 16);
        u.y = (unsigned int)f2bf(av[j][2] + b_v.z) | ((unsigned int)f2bf(av[j][3] + b_v.w) << 16);
        *(uint2*)&v_t[swz(j * 16 + l16, colb)] = u;
      }
    }
    __syncthreads();

    // ---- phase 2: attention. thread = (head h, row r, half p); pair shares (h,r).
    {
      const int p  = t & 1;               // channel half (16 ch each)
      const int r  = (t >> 1) & 63;
      const int h  = t >> 7;
      const int dil = d + 1;
      const int n = (row0 + r) & (SEQ - 1);
      const int c0 = h * HD + p * 16;     // col within the 128-ch group

      float qv[16];
#pragma unroll
      for (int c = 0; c < 4; ++c) {
        uint2 u = *(const uint2*)&q_t[swz(r, c0 + c * 4)];
        unpack4(u, &qv[c * 4]);
      }

      float ex[3];
      int   valid[3];
#pragma unroll
      for (int kh = 0; kh < 3; ++kh) {
        int off = (kh - 1) * dil;
        int nn = n + off;
        int vd = (nn >= 0) && (nn < SEQ);
        valid[kh] = vd;
        float partial = 0.f;
        if (vd) {
#pragma unroll
          for (int c = 0; c < 4; ++c) {
            uint2 u = *(const uint2*)&k_t[swz(r + 16 + off, c0 + c * 4)];
            float kv[4]; unpack4(u, kv);
#pragma unroll
            for (int j = 0; j < 4; ++j) partial += qv[c * 4 + j] * kv[j];
          }
        }
        float full = partial + __shfl_xor(partial, 1);   // pair has same (h,r,valid)
        ex[kh] = vd ? __expf(full * SCALE) : 1.f;        // zero-padded tap -> exp(0)=1
      }
      float inv = 1.f / (ex[0] + ex[1] + ex[2] + 6.f);   // +6 structural zero taps

      float o[16] = {};
#pragma unroll
      for (int kh = 0; kh < 3; ++kh) {
        if (!valid[kh]) continue;
        int off = (kh - 1) * dil;
        float wgt = ex[kh];
#pragma unroll
        for (int c = 0; c < 4; ++c) {
          uint2 u = *(const uint2*)&v_t[swz(r + 16 + off, c0 + c * 4)];
          float vv[4]; unpack4(u, vv);
#pragma unroll
          for (int j = 0; j < 4; ++j) o[c * 4 + j] += wgt * vv[j];
        }
      }

      // attn tile write (fragment-major): 2 chunks of 8 ch
      int ch0 = d * CD + c0;
      unsigned short* op = a_t + ((r >> 4) * KB8 + (ch0 >> 3)) * 128 + (r & 15) * 8;
#pragma unroll
      for (int c = 0; c < 2; ++c) {
        uint4 u;
        u.x = (unsigned int)f2bf(o[c*8+0] * inv) | ((unsigned int)f2bf(o[c*8+1] * inv) << 16);
        u.y = (unsigned int)f2bf(o[c*8+2] * inv) | ((unsigned int)f2bf(o[c*8+3] * inv) << 16);
        u.z = (unsigned int)f2bf(o[c*8+4] * inv) | ((unsigned int)f2bf(o[c*8+5] * inv) << 16);
        u.w = (unsigned int)f2bf(o[c*8+6] * inv) | ((unsigned int)f2bf(o[c*8+7] * inv) << 16);
        *(uint4*)(op + c * 128) = u;
      }
    }
    __syncthreads();   // protects qkv tiles for next d AND attn tile before phase 3
  }

  // ---- phase 3: out = attn @ Wproj^T + bproj. Wave w -> out cols w*48..w*48+47.
  {
    const unsigned short* pw[3];
#pragma unroll
    for (int c = 0; c < 3; ++c)
      pw[c] = Wp + (size_t)(w * 3 + c) * FRAG_STRIDE + lane * 8;

    f32x4 oc[4][3] = {};
#pragma unroll
    for (int kk = 0; kk < 12; ++kk) {
      bf16x8 af[4];
#pragma unroll
      for (int mi = 0; mi < 4; ++mi)
        af[mi] = *(const bf16x8*)&a_t[(mi * KB8 + kk * 4) * 128 + lane * 8];
      bf16x8 bf[3];
#pragma unroll
      for (int c = 0; c < 3; ++c) bf[c] = *(const bf16x8*)(pw[c] + kk * 512);
#pragma unroll
      for (int mi = 0; mi < 4; ++mi)
#pragma unroll
        for (int c = 0; c < 3; ++c)
          oc[mi][c] = __builtin_amdgcn_mfma_f32_16x16x32_bf16(bf[c], af[mi], oc[mi][c], 0, 0, 0);
    }

    float4 bb[3];
#pragma unroll
    for (int c = 0; c < 3; ++c)
      bb[c] = *(const float4*)&bproj[w * 48 + c * 16 + quad * 4];

#pragma unroll
    for (int mi = 0; mi < 4; ++mi) {
      size_t gr = (size_t)(row0 + mi * 16 + l16);
#pragma unroll
      for (int c = 0; c < 3; ++c) {
        int gc = w * 48 + c * 16 + quad * 4;
        float4 o;
        o.x = oc[mi][c][0] + bb[c].x;
        o.y = oc[mi][c][1] + bb[c].y;
        o.z = oc[mi][c][2] + bb[c].z;
        o.w = oc[mi][c][3] + bb[c].w;
        *(float4*)&out[gr * DIM + gc] = o;
      }
    }
  }
}

// ---------------- launch ----------------
extern "C" void kernel_launch(void* const* d_in, const int* in_sizes, int n_in,
                              void* d_out, int out_size, void* d_ws, size_t ws_size,
                              hipStream_t stream) {
  const float* x     = (const float*)d_in[0];
  const float* Wqkv  = (const float*)d_in[1];
  const float* bqkv  = (const float*)d_in[2];
  const float* Wproj = (const float*)d_in[3];
  const float* bproj = (const float*)d_in[4];
  float* out = (float*)d_out;

  char* ws = (char*)d_ws;
  unsigned short* x_swz     = (unsigned short*)(ws);                // 25,165,824 B
  unsigned short* wqkv_swz  = (unsigned short*)(ws + 25165824);     //    884,736 B
  unsigned short* wproj_swz = (unsigned short*)(ws + 26050560);     //    294,912 B

  // convert all three fp32 tensors into swizzled fragment-major bf16 (one launch)
  cvt_all<<<6432, 256, 0, stream>>>(x, Wqkv, Wproj, x_swz, wqkv_swz, wproj_swz);

  // fully fused: qkv projection + dilated attention + output projection
  fused_all<<<dim3(ROWS / 64), 512, 0, stream>>>(x_swz, wqkv_swz, bqkv,
                                                 wproj_swz, bproj, out);
}

// Round 3
// 178.927 us; speedup vs baseline: 1.5433x; 1.5433x over previous
//
#include <hip/hip_runtime.h>

// ---------------- problem constants ----------------
#define DIM     384
#define QKV_CH  1152          // 3*DIM
#define HD      32            // head dim
#define CD      128           // channels per dilation group (4 heads)
#define BATCH   4
#define SEQ     8192
#define ROWS    (BATCH*SEQ)   // 32768
#define SCALE   0.17677669529663687f   // 32^-0.5

#define KB8         48            // K/8 for K=384
#define FRAG_STRIDE (KB8*128)     // 6144 shorts per 16-row block in swizzled layout
#define XRB_MAX     (ROWS/16 - 1) // 2047

typedef short bf16x8 __attribute__((ext_vector_type(8)));
typedef float f32x4  __attribute__((ext_vector_type(4)));

__device__ __forceinline__ unsigned short f2bf(float f) {
  unsigned int u = __float_as_uint(f);
  u += 0x7fffu + ((u >> 16) & 1u);      // RNE
  return (unsigned short)(u >> 16);
}
__device__ __forceinline__ float bf2f(unsigned short b) {
  return __uint_as_float(((unsigned int)b) << 16);
}
__device__ __forceinline__ void unpack4(uint2 u, float* f) {
  f[0] = bf2f((unsigned short)(u.x & 0xffffu)); f[1] = bf2f((unsigned short)(u.x >> 16));
  f[2] = bf2f((unsigned short)(u.y & 0xffffu)); f[3] = bf2f((unsigned short)(u.y >> 16));
}

// LDS XOR swizzle: tile row stride 128 shorts (256B, no pad). XOR short-index
// bits 2..6 with (row&31) -> 8B-granule permutation within the row.
__device__ __forceinline__ int swz(int row, int col) {   // col multiple of 4
  return (row * 128 + col) ^ ((row & 31) << 2);
}

// ================= global swizzled (fragment-major) layout =================
// swz_g(r,k; K=384) = ((r/16)*48 + k/8)*128 + (r%16)*8 + (k%8)
// MFMA fragment (16 rows x 32 k) = base + lane*8 shorts, one coalesced 1KB wave load.

// ---------------- fp32 -> swizzled bf16 convert (x, Wqkv, Wproj in one launch) ----------------
__global__ __launch_bounds__(256) void cvt_all(const float* __restrict__ x,
                                               const float* __restrict__ wqkv,
                                               const float* __restrict__ wproj,
                                               unsigned short* __restrict__ xo,
                                               unsigned short* __restrict__ qo,
                                               unsigned short* __restrict__ po) {
  int cid = blockIdx.x * 256 + threadIdx.x;
  const float* in; unsigned short* out;
  if (cid < 1572864) { in = x; out = xo; }                         // 32768*48 chunks
  else if (cid < 1628160) { cid -= 1572864; in = wqkv; out = qo; } // 1152*48
  else { cid -= 1628160; in = wproj; out = po; }                   // 384*48
  int rl = cid & 15;
  int q  = cid >> 4;
  int rb = q / KB8;
  int kb = q - rb * KB8;
  const float* p = in + (size_t)(rb * 16 + rl) * DIM + kb * 8;
  float4 a = *(const float4*)p;
  float4 b = *(const float4*)(p + 4);
  uint4 u;
  u.x = (unsigned int)f2bf(a.x) | ((unsigned int)f2bf(a.y) << 16);
  u.y = (unsigned int)f2bf(a.z) | ((unsigned int)f2bf(a.w) << 16);
  u.z = (unsigned int)f2bf(b.x) | ((unsigned int)f2bf(b.y) << 16);
  u.w = (unsigned int)f2bf(b.z) | ((unsigned int)f2bf(b.w) << 16);
  *(uint4*)(out + (size_t)cid * 8) = u;
}

// ---------------- bf16 MFMA GEMM (register-direct, swizzled inputs) ----------------
// R0-verified kernel. Grid is launched (col-tiles, row-tiles) so the 3 col-tiles
// sharing an A row-panel are dispatch-adjacent -> L3/L2-coincident A reuse.
template<int OUT_BF16, int K, int NT>
__global__ __launch_bounds__(256) void gemm_swz(const unsigned short* __restrict__ A,
                                                const unsigned short* __restrict__ Bt,
                                                const float* __restrict__ bias,
                                                void* __restrict__ Cv) {
  const int KB = K / 8;
  const int t = threadIdx.x;
  const int wave = t >> 6, lane = t & 63;
  const int quad = lane >> 4, l16 = lane & 15;
  const int row0 = blockIdx.y * 128, col0 = blockIdx.x * 128;
  const int wm = (wave & 1) * 64, wn = (wave >> 1) * 64;

  const unsigned short* PA[4];
  const unsigned short* PB[4];
#pragma unroll
  for (int mi = 0; mi < 4; ++mi)
    PA[mi] = A + (size_t)(((row0 + wm) >> 4) + mi) * KB * 128 + lane * 8;
#pragma unroll
  for (int ni = 0; ni < 4; ++ni)
    PB[ni] = Bt + (size_t)(((col0 + wn) >> 4) + ni) * KB * 128 + lane * 8;

  f32x4 acc[4][4] = {};

#pragma unroll
  for (int kk = 0; kk < K / 32; ++kk) {
    bf16x8 af[4], bfv[4];
#pragma unroll
    for (int mi = 0; mi < 4; ++mi) af[mi]  = *(const bf16x8*)(PA[mi] + kk * 512);
#pragma unroll
    for (int ni = 0; ni < 4; ++ni) bfv[ni] = *(const bf16x8*)(PB[ni] + kk * 512);
#pragma unroll
    for (int mi = 0; mi < 4; ++mi)
#pragma unroll
      for (int ni = 0; ni < 4; ++ni)
        acc[mi][ni] = __builtin_amdgcn_mfma_f32_16x16x32_bf16(bfv[ni], af[mi], acc[mi][ni], 0, 0, 0);
  }

  float4 bv[4];
#pragma unroll
  for (int ni = 0; ni < 4; ++ni)
    bv[ni] = *(const float4*)&bias[col0 + wn + ni * 16 + quad * 4];

#pragma unroll
  for (int mi = 0; mi < 4; ++mi) {
    size_t gr = (size_t)(row0 + wm + mi * 16 + l16);
#pragma unroll
    for (int ni = 0; ni < 4; ++ni) {
      int gc = col0 + wn + ni * 16 + quad * 4;
      float v0 = acc[mi][ni][0] + bv[ni].x;
      float v1 = acc[mi][ni][1] + bv[ni].y;
      float v2 = acc[mi][ni][2] + bv[ni].z;
      float v3 = acc[mi][ni][3] + bv[ni].w;
      if (OUT_BF16) {
        uint2 u;
        u.x = (unsigned int)f2bf(v0) | ((unsigned int)f2bf(v1) << 16);
        u.y = (unsigned int)f2bf(v2) | ((unsigned int)f2bf(v3) << 16);
        *(uint2*)&((unsigned short*)Cv)[gr * NT + gc] = u;
      } else {
        float4 o; o.x = v0; o.y = v1; o.z = v2; o.w = v3;
        *(float4*)&((float*)Cv)[gr * NT + gc] = o;
      }
    }
  }
}

// ---------------- fused QKV-projection + dilated attention ----------------
// R1 structure, ONE change: __launch_bounds__(512, 2) -> 256-reg cap on the
// unified VGPR+AGPR file. R1's (512,4)=128-reg cap forced a catastrophic
// scratch spill (hbm_bytes 25MB -> 392MB); live set here is ~165 regs.
// 512 threads = 8 waves; wave w owns ONE 16-col block of q (4 rb), k (6 rb),
// v (6 rb): acc = 16 f32x4 = 64 regs. LDS 64KB -> 2 blocks/CU, 2 waves/SIMD.
// Phase 2: 2 threads per (head,row), 16 channels each; 32-dim dot via shfl_xor.
__global__ __launch_bounds__(512, 2) void fused_qkv_attn(
    const unsigned short* __restrict__ X,     // x_swz    [ROWS,384] swizzled
    const unsigned short* __restrict__ W,     // wqkv_swz [1152,384] swizzled
    const float* __restrict__ bqkv,           // [1152]
    unsigned short* __restrict__ out) {       // attn_swz [ROWS,384] swizzled
  __shared__ unsigned short sm[32768];        // 65536 B
  unsigned short* q_t = sm;                   // 64 rows x 128 (XOR-swizzled)
  unsigned short* k_t = sm + 64 * 128;        // 96 rows (row0-16 .. row0+80)
  unsigned short* v_t = sm + 160 * 128;       // 96 rows

  const int t = threadIdx.x;
  const int w = t >> 6, lane = t & 63;
  const int quad = lane >> 4, l16 = lane & 15;
  const int d = blockIdx.y;
  const int row0 = blockIdx.x * 64;
  const int rb0 = row0 >> 4;

  // ---- phase 1: MFMA. wave w -> col-block w (16 cols) of q,k,v; all row-blocks.
  const unsigned short* pa[6];
#pragma unroll
  for (int j = 0; j < 6; ++j) {
    int xrb = rb0 - 1 + j;                               // halo row-blocks, clamped
    xrb = xrb < 0 ? 0 : (xrb > XRB_MAX ? XRB_MAX : xrb); // at global edges (masked taps)
    pa[j] = X + (size_t)xrb * FRAG_STRIDE + lane * 8;
  }
  const int wrb = d * 8 + w;                             // weight row-block (channel/16)
  const unsigned short* pbq = W + (size_t)wrb * FRAG_STRIDE + lane * 8;
  const unsigned short* pbk = pbq + (size_t)24 * FRAG_STRIDE;
  const unsigned short* pbv = pbq + (size_t)48 * FRAG_STRIDE;

  f32x4 aq[4] = {}, ak[6] = {}, av[6] = {};

#pragma unroll
  for (int kk = 0; kk < 12; ++kk) {
    bf16x8 a[6];
#pragma unroll
    for (int j = 0; j < 6; ++j) a[j] = *(const bf16x8*)(pa[j] + kk * 512);
    bf16x8 bq = *(const bf16x8*)(pbq + kk * 512);
    bf16x8 bk = *(const bf16x8*)(pbk + kk * 512);
    bf16x8 bv = *(const bf16x8*)(pbv + kk * 512);
#pragma unroll
    for (int j = 0; j < 4; ++j)
      aq[j] = __builtin_amdgcn_mfma_f32_16x16x32_bf16(bq, a[j + 1], aq[j], 0, 0, 0);
#pragma unroll
    for (int j = 0; j < 6; ++j)
      ak[j] = __builtin_amdgcn_mfma_f32_16x16x32_bf16(bk, a[j], ak[j], 0, 0, 0);
#pragma unroll
    for (int j = 0; j < 6; ++j)
      av[j] = __builtin_amdgcn_mfma_f32_16x16x32_bf16(bv, a[j], av[j], 0, 0, 0);
  }

  // ---- epilogue: bias + bf16 + swizzled LDS stage. lane: row l16, cols colb+reg.
  const int colb = w * 16 + quad * 4;
  {
    float4 b_q = *(const float4*)&bqkv[d * CD + colb];
    float4 b_k = *(const float4*)&bqkv[384 + d * CD + colb];
    float4 b_v = *(const float4*)&bqkv[768 + d * CD + colb];
#pragma unroll
    for (int j = 0; j < 4; ++j) {
      uint2 u;
      u.x = (unsigned int)f2bf(aq[j][0] + b_q.x) | ((unsigned int)f2bf(aq[j][1] + b_q.y) << 16);
      u.y = (unsigned int)f2bf(aq[j][2] + b_q.z) | ((unsigned int)f2bf(aq[j][3] + b_q.w) << 16);
      *(uint2*)&q_t[swz(j * 16 + l16, colb)] = u;
    }
#pragma unroll
    for (int j = 0; j < 6; ++j) {
      uint2 u;
      u.x = (unsigned int)f2bf(ak[j][0] + b_k.x) | ((unsigned int)f2bf(ak[j][1] + b_k.y) << 16);
      u.y = (unsigned int)f2bf(ak[j][2] + b_k.z) | ((unsigned int)f2bf(ak[j][3] + b_k.w) << 16);
      *(uint2*)&k_t[swz(j * 16 + l16, colb)] = u;
    }
#pragma unroll
    for (int j = 0; j < 6; ++j) {
      uint2 u;
      u.x = (unsigned int)f2bf(av[j][0] + b_v.x) | ((unsigned int)f2bf(av[j][1] + b_v.y) << 16);
      u.y = (unsigned int)f2bf(av[j][2] + b_v.z) | ((unsigned int)f2bf(av[j][3] + b_v.w) << 16);
      *(uint2*)&v_t[swz(j * 16 + l16, colb)] = u;
    }
  }
  __syncthreads();

  // ---- phase 2: attention. thread = (head h, row r, half p); pair shares (h,r).
  const int p  = t & 1;               // channel half (16 ch each)
  const int r  = (t >> 1) & 63;
  const int h  = t >> 7;
  const int dil = d + 1;
  const int n = (row0 + r) & (SEQ - 1);
  const int c0 = h * HD + p * 16;     // col within the 128-ch group

  float q[16];
#pragma unroll
  for (int c = 0; c < 4; ++c) {
    uint2 u = *(const uint2*)&q_t[swz(r, c0 + c * 4)];
    unpack4(u, &q[c * 4]);
  }

  float ex[3];
  int   valid[3];
#pragma unroll
  for (int kh = 0; kh < 3; ++kh) {
    int off = (kh - 1) * dil;
    int nn = n + off;
    int v = (nn >= 0) && (nn < SEQ);
    valid[kh] = v;
    float partial = 0.f;
    if (v) {
#pragma unroll
      for (int c = 0; c < 4; ++c) {
        uint2 u = *(const uint2*)&k_t[swz(r + 16 + off, c0 + c * 4)];
        float kv[4]; unpack4(u, kv);
#pragma unroll
        for (int j = 0; j < 4; ++j) partial += q[c * 4 + j] * kv[j];
      }
    }
    float full = partial + __shfl_xor(partial, 1);   // pair has same (h,r,valid)
    ex[kh] = v ? __expf(full * SCALE) : 1.f;          // zero-padded tap -> exp(0)=1
  }
  float inv = 1.f / (ex[0] + ex[1] + ex[2] + 6.f);    // +6 structural zero taps

  float o[16] = {};
#pragma unroll
  for (int kh = 0; kh < 3; ++kh) {
    if (!valid[kh]) continue;
    int off = (kh - 1) * dil;
    float wgt = ex[kh];
#pragma unroll
    for (int c = 0; c < 4; ++c) {
      uint2 u = *(const uint2*)&v_t[swz(r + 16 + off, c0 + c * 4)];
      float vv[4]; unpack4(u, vv);
#pragma unroll
      for (int j = 0; j < 4; ++j) o[c * 4 + j] += wgt * vv[j];
    }
  }

  // swizzled global write: 2 chunks of 8 ch; 16 consecutive rows -> 256B contiguous
  int row = row0 + r;
  int ch0 = d * CD + c0;
  unsigned short* op = out + ((size_t)(row >> 4) * KB8 + (ch0 >> 3)) * 128 + (row & 15) * 8;
#pragma unroll
  for (int c = 0; c < 2; ++c) {
    uint4 u;
    u.x = (unsigned int)f2bf(o[c*8+0] * inv) | ((unsigned int)f2bf(o[c*8+1] * inv) << 16);
    u.y = (unsigned int)f2bf(o[c*8+2] * inv) | ((unsigned int)f2bf(o[c*8+3] * inv) << 16);
    u.z = (unsigned int)f2bf(o[c*8+4] * inv) | ((unsigned int)f2bf(o[c*8+5] * inv) << 16);
    u.w = (unsigned int)f2bf(o[c*8+6] * inv) | ((unsigned int)f2bf(o[c*8+7] * inv) << 16);
    *(uint4*)(op + c * 128) = u;
  }
}

// ---------------- launch ----------------
extern "C" void kernel_launch(void* const* d_in, const int* in_sizes, int n_in,
                              void* d_out, int out_size, void* d_ws, size_t ws_size,
                              hipStream_t stream) {
  const float* x     = (const float*)d_in[0];
  const float* Wqkv  = (const float*)d_in[1];
  const float* bqkv  = (const float*)d_in[2];
  const float* Wproj = (const float*)d_in[3];
  const float* bproj = (const float*)d_in[4];
  float* out = (float*)d_out;

  char* ws = (char*)d_ws;
  unsigned short* x_swz     = (unsigned short*)(ws);                // 25,165,824 B
  unsigned short* attn_swz  = (unsigned short*)(ws + 25165824);     // 25,165,824 B
  unsigned short* wqkv_swz  = (unsigned short*)(ws + 50331648);     //    884,736 B
  unsigned short* wproj_swz = (unsigned short*)(ws + 51216384);     //    294,912 B

  // convert all three fp32 tensors into swizzled fragment-major bf16 (one launch)
  cvt_all<<<6432, 256, 0, stream>>>(x, Wqkv, Wproj, x_swz, wqkv_swz, wproj_swz);

  // fused qkv-projection + dilated attention (qkv never hits HBM)
  fused_qkv_attn<<<dim3(ROWS / 64, 3), 512, 0, stream>>>(x_swz, wqkv_swz, bqkv, attn_swz);

  // out = attn @ Wproj^T + bproj  (fp32 row-major out); col-tiles dispatch-fastest
  gemm_swz<0, DIM, DIM><<<dim3(DIM / 128, ROWS / 128), 256, 0, stream>>>(
      attn_swz, wproj_swz, bproj, (void*)out);
}

// Round 4
// 167.313 us; speedup vs baseline: 1.6504x; 1.0694x over previous
//
#include <hip/hip_runtime.h>

// ---------------- problem constants ----------------
#define DIM     384
#define QKV_CH  1152          // 3*DIM
#define HD      32            // head dim
#define CD      128           // channels per dilation group (4 heads)
#define BATCH   4
#define SEQ     8192
#define ROWS    (BATCH*SEQ)   // 32768
#define SCALE   0.17677669529663687f   // 32^-0.5

#define KB8         48            // K/8 for K=384
#define FRAG_STRIDE (KB8*128)     // 6144 shorts per 16-row block in swizzled layout
#define XRB_MAX     (ROWS/16 - 1) // 2047
#define LSTR        136           // LDS tile row stride in shorts (272B: 8B and 16B aligned)

typedef short bf16x8 __attribute__((ext_vector_type(8)));
typedef float f32x4  __attribute__((ext_vector_type(4)));

__device__ __forceinline__ unsigned short f2bf(float f) {
  unsigned int u = __float_as_uint(f);
  u += 0x7fffu + ((u >> 16) & 1u);      // RNE
  return (unsigned short)(u >> 16);
}
__device__ __forceinline__ float bf2f(unsigned short b) {
  return __uint_as_float(((unsigned int)b) << 16);
}
__device__ __forceinline__ void unpack4(uint2 u, float* f) {
  f[0] = bf2f((unsigned short)(u.x & 0xffffu)); f[1] = bf2f((unsigned short)(u.x >> 16));
  f[2] = bf2f((unsigned short)(u.y & 0xffffu)); f[3] = bf2f((unsigned short)(u.y >> 16));
}

// ================= global swizzled (fragment-major) layout =================
// swz_g(r,k; K=384) = ((r/16)*48 + k/8)*128 + (r%16)*8 + (k%8)
// MFMA fragment (16 rows x 32 k) = base + lane*8 shorts, one coalesced 1KB wave load.

// ---------------- fp32 -> swizzled bf16 convert (x, Wqkv, Wproj in one launch) ----------------
__global__ __launch_bounds__(256) void cvt_all(const float* __restrict__ x,
                                               const float* __restrict__ wqkv,
                                               const float* __restrict__ wproj,
                                               unsigned short* __restrict__ xo,
                                               unsigned short* __restrict__ qo,
                                               unsigned short* __restrict__ po) {
  int cid = blockIdx.x * 256 + threadIdx.x;
  const float* in; unsigned short* out;
  if (cid < 1572864) { in = x; out = xo; }                         // 32768*48 chunks
  else if (cid < 1628160) { cid -= 1572864; in = wqkv; out = qo; } // 1152*48
  else { cid -= 1628160; in = wproj; out = po; }                   // 384*48
  int rl = cid & 15;
  int q  = cid >> 4;
  int rb = q / KB8;
  int kb = q - rb * KB8;
  const float* p = in + (size_t)(rb * 16 + rl) * DIM + kb * 8;
  float4 a = *(const float4*)p;
  float4 b = *(const float4*)(p + 4);
  uint4 u;
  u.x = (unsigned int)f2bf(a.x) | ((unsigned int)f2bf(a.y) << 16);
  u.y = (unsigned int)f2bf(a.z) | ((unsigned int)f2bf(a.w) << 16);
  u.z = (unsigned int)f2bf(b.x) | ((unsigned int)f2bf(b.y) << 16);
  u.w = (unsigned int)f2bf(b.z) | ((unsigned int)f2bf(b.w) << 16);
  *(uint4*)(out + (size_t)cid * 8) = u;
}

// ---------------- bf16 MFMA GEMM (register-direct, swizzled inputs) ----------------
// R0-verified body. Grid launched (col-tiles, row-tiles): the 3 col-tiles
// sharing an A row-panel are dispatch-adjacent -> L2-coincident A reuse.
template<int OUT_BF16, int K, int NT>
__global__ __launch_bounds__(256) void gemm_swz(const unsigned short* __restrict__ A,
                                                const unsigned short* __restrict__ Bt,
                                                const float* __restrict__ bias,
                                                void* __restrict__ Cv) {
  const int KB = K / 8;
  const int t = threadIdx.x;
  const int wave = t >> 6, lane = t & 63;
  const int quad = lane >> 4, l16 = lane & 15;
  const int row0 = blockIdx.y * 128, col0 = blockIdx.x * 128;
  const int wm = (wave & 1) * 64, wn = (wave >> 1) * 64;

  const unsigned short* PA[4];
  const unsigned short* PB[4];
#pragma unroll
  for (int mi = 0; mi < 4; ++mi)
    PA[mi] = A + (size_t)(((row0 + wm) >> 4) + mi) * KB * 128 + lane * 8;
#pragma unroll
  for (int ni = 0; ni < 4; ++ni)
    PB[ni] = Bt + (size_t)(((col0 + wn) >> 4) + ni) * KB * 128 + lane * 8;

  f32x4 acc[4][4] = {};

#pragma unroll
  for (int kk = 0; kk < K / 32; ++kk) {
    bf16x8 af[4], bfv[4];
#pragma unroll
    for (int mi = 0; mi < 4; ++mi) af[mi]  = *(const bf16x8*)(PA[mi] + kk * 512);
#pragma unroll
    for (int ni = 0; ni < 4; ++ni) bfv[ni] = *(const bf16x8*)(PB[ni] + kk * 512);
#pragma unroll
    for (int mi = 0; mi < 4; ++mi)
#pragma unroll
      for (int ni = 0; ni < 4; ++ni)
        acc[mi][ni] = __builtin_amdgcn_mfma_f32_16x16x32_bf16(bfv[ni], af[mi], acc[mi][ni], 0, 0, 0);
  }

  float4 bv[4];
#pragma unroll
  for (int ni = 0; ni < 4; ++ni)
    bv[ni] = *(const float4*)&bias[col0 + wn + ni * 16 + quad * 4];

#pragma unroll
  for (int mi = 0; mi < 4; ++mi) {
    size_t gr = (size_t)(row0 + wm + mi * 16 + l16);
#pragma unroll
    for (int ni = 0; ni < 4; ++ni) {
      int gc = col0 + wn + ni * 16 + quad * 4;
      float v0 = acc[mi][ni][0] + bv[ni].x;
      float v1 = acc[mi][ni][1] + bv[ni].y;
      float v2 = acc[mi][ni][2] + bv[ni].z;
      float v3 = acc[mi][ni][3] + bv[ni].w;
      if (OUT_BF16) {
        uint2 u;
        u.x = (unsigned int)f2bf(v0) | ((unsigned int)f2bf(v1) << 16);
        u.y = (unsigned int)f2bf(v2) | ((unsigned int)f2bf(v3) << 16);
        *(uint2*)&((unsigned short*)Cv)[gr * NT + gc] = u;
      } else {
        float4 o; o.x = v0; o.y = v1; o.z = v2; o.w = v3;
        *(float4*)&((float*)Cv)[gr * NT + gc] = o;
      }
    }
  }
}

// ---------------- fused QKV-projection + dilated attention ----------------
// R0-verified body (54 us: 256 threads, 2 col-blocks/wave, LSTR-padded LDS,
// acc 128 + arch 128 = exactly the 2-wave/SIMD 256-reg cap). ONE change vs R0:
// XCD-chunked blockIdx.x swizzle (T1) -- 512 row-tiles / 8 XCDs = 64 contiguous
// tiles per XCD (~3.2 MB x-span, fits 4 MB XCD-L2); the d=1,2 dispatch passes
// re-hit the same L2 lines, and halo-sharing neighbors stay on one XCD.
// Round-3 evidence: FETCH 58.7 MB vs 25 MB unique -> latency-exposed refetch.
__global__ __launch_bounds__(256, 2) void fused_qkv_attn(
    const unsigned short* __restrict__ X,     // x_swz    [ROWS,384] swizzled
    const unsigned short* __restrict__ W,     // wqkv_swz [1152,384] swizzled
    const float* __restrict__ bqkv,           // [1152]
    unsigned short* __restrict__ out) {       // attn_swz [ROWS,384] swizzled
  __shared__ unsigned short sm[34816];        // 69632 B
  unsigned short* q_t = sm;                   // 64 rows x LSTR
  unsigned short* k_t = sm + 64 * LSTR;       // 96 rows (rows row0-16..row0+80)
  unsigned short* v_t = sm + 160 * LSTR;      // 96 rows

  const int t = threadIdx.x;
  const int w = t >> 6, lane = t & 63;
  const int quad = lane >> 4, l16 = lane & 15;
  const int d = blockIdx.y;
  // XCD-chunked bijective swizzle: gridDim.x = 512 = 8 * 64
  const int bx = blockIdx.x;
  const int row0 = (((bx & 7) << 6) + (bx >> 3)) * 64;
  const int rb0 = row0 >> 4;

  // ---- phase 1: MFMA. wave w owns output cols w*32..w*32+32 (2 col-blocks)
  // for ALL row-blocks of q (4), k (6), v (6). k/v reuse q's x-fragments.
  const unsigned short* pa[6];
#pragma unroll
  for (int j = 0; j < 6; ++j) {
    int xrb = rb0 - 1 + j;                         // halo row-blocks, clamped at
    xrb = xrb < 0 ? 0 : (xrb > XRB_MAX ? XRB_MAX : xrb);  // global edges (unused taps)
    pa[j] = X + (size_t)xrb * FRAG_STRIDE + lane * 8;
  }
  const unsigned short *pbq[2], *pbk[2], *pbv[2];
#pragma unroll
  for (int c = 0; c < 2; ++c) {
    int wrb = d * 8 + w * 2 + c;                   // weight row-block (channel/16)
    pbq[c] = W + (size_t)wrb * FRAG_STRIDE + lane * 8;
    pbk[c] = W + (size_t)(wrb + 24) * FRAG_STRIDE + lane * 8;
    pbv[c] = W + (size_t)(wrb + 48) * FRAG_STRIDE + lane * 8;
  }

  f32x4 aq[4][2] = {}, ak[6][2] = {}, av[6][2] = {};

#pragma unroll
  for (int kk = 0; kk < 12; ++kk) {
    bf16x8 a[6];
#pragma unroll
    for (int j = 0; j < 6; ++j) a[j] = *(const bf16x8*)(pa[j] + kk * 512);
    bf16x8 bq[2], bk[2], bv[2];
#pragma unroll
    for (int c = 0; c < 2; ++c) {
      bq[c] = *(const bf16x8*)(pbq[c] + kk * 512);
      bk[c] = *(const bf16x8*)(pbk[c] + kk * 512);
      bv[c] = *(const bf16x8*)(pbv[c] + kk * 512);
    }
#pragma unroll
    for (int c = 0; c < 2; ++c) {
#pragma unroll
      for (int j = 0; j < 4; ++j)
        aq[j][c] = __builtin_amdgcn_mfma_f32_16x16x32_bf16(bq[c], a[j + 1], aq[j][c], 0, 0, 0);
#pragma unroll
      for (int j = 0; j < 6; ++j)
        ak[j][c] = __builtin_amdgcn_mfma_f32_16x16x32_bf16(bk[c], a[j], ak[j][c], 0, 0, 0);
#pragma unroll
      for (int j = 0; j < 6; ++j)
        av[j][c] = __builtin_amdgcn_mfma_f32_16x16x32_bf16(bv[c], a[j], av[j][c], 0, 0, 0);
    }
  }

  // ---- epilogue: bias + bf16 + LDS stage. lane holds row l16, cols quad*4+reg.
#pragma unroll
  for (int c = 0; c < 2; ++c) {
    int colb = w * 32 + c * 16 + quad * 4;
    float4 b_q = *(const float4*)&bqkv[d * CD + colb];
    float4 b_k = *(const float4*)&bqkv[384 + d * CD + colb];
    float4 b_v = *(const float4*)&bqkv[768 + d * CD + colb];
#pragma unroll
    for (int j = 0; j < 4; ++j) {
      uint2 u;
      u.x = (unsigned int)f2bf(aq[j][c][0] + b_q.x) | ((unsigned int)f2bf(aq[j][c][1] + b_q.y) << 16);
      u.y = (unsigned int)f2bf(aq[j][c][2] + b_q.z) | ((unsigned int)f2bf(aq[j][c][3] + b_q.w) << 16);
      *(uint2*)&q_t[(j * 16 + l16) * LSTR + colb] = u;
    }
#pragma unroll
    for (int j = 0; j < 6; ++j) {
      uint2 u;
      u.x = (unsigned int)f2bf(ak[j][c][0] + b_k.x) | ((unsigned int)f2bf(ak[j][c][1] + b_k.y) << 16);
      u.y = (unsigned int)f2bf(ak[j][c][2] + b_k.z) | ((unsigned int)f2bf(ak[j][c][3] + b_k.w) << 16);
      *(uint2*)&k_t[(j * 16 + l16) * LSTR + colb] = u;
    }
#pragma unroll
    for (int j = 0; j < 6; ++j) {
      uint2 u;
      u.x = (unsigned int)f2bf(av[j][c][0] + b_v.x) | ((unsigned int)f2bf(av[j][c][1] + b_v.y) << 16);
      u.y = (unsigned int)f2bf(av[j][c][2] + b_v.z) | ((unsigned int)f2bf(av[j][c][3] + b_v.w) << 16);
      *(uint2*)&v_t[(j * 16 + l16) * LSTR + colb] = u;
    }
  }
  __syncthreads();

  // ---- phase 2: attention. thread = (head h = wave, row r = lane..) over 64 rows.
  const int h = t >> 6;
  const int r = t & 63;
  const int dil = d + 1;
  const int n = (row0 + r) & (SEQ - 1);

  float q[32];
  {
    const uint2* qp = (const uint2*)&q_t[r * LSTR + h * HD];
#pragma unroll
    for (int c = 0; c < 8; ++c) unpack4(qp[c], &q[c * 4]);
  }

  float ex[3];
  int   valid[3];
#pragma unroll
  for (int kh = 0; kh < 3; ++kh) {
    int off = (kh - 1) * dil;
    int nn = n + off;
    int v = (nn >= 0) && (nn < SEQ);
    valid[kh] = v;
    float l = 0.f;
    if (v) {
      const uint2* kp = (const uint2*)&k_t[(r + 16 + off) * LSTR + h * HD];
#pragma unroll
      for (int c = 0; c < 8; ++c) {
        float kkv[4]; unpack4(kp[c], kkv);
#pragma unroll
        for (int j = 0; j < 4; ++j) l += q[c * 4 + j] * kkv[j];
      }
    }
    ex[kh] = v ? __expf(l * SCALE) : 1.f;   // zero-padded tap -> exp(0)=1
  }
  float inv = 1.f / (ex[0] + ex[1] + ex[2] + 6.f);  // +6 structural zero taps

  float o[32];
#pragma unroll
  for (int e = 0; e < 32; ++e) o[e] = 0.f;
#pragma unroll
  for (int kh = 0; kh < 3; ++kh) {
    if (!valid[kh]) continue;
    int off = (kh - 1) * dil;
    const uint2* vp = (const uint2*)&v_t[(r + 16 + off) * LSTR + h * HD];
    float wgt = ex[kh];
#pragma unroll
    for (int c = 0; c < 8; ++c) {
      float vv[4]; unpack4(vp[c], vv);
#pragma unroll
      for (int j = 0; j < 4; ++j) o[c * 4 + j] += wgt * vv[j];
    }
  }

  // swizzled global write: 4 chunks of 8 ch; 16 consecutive rows -> 256B contiguous
  int row = row0 + r;
  int ch0 = d * CD + h * HD;
  unsigned short* op = out + ((size_t)(row >> 4) * KB8 + (ch0 >> 3)) * 128 + (row & 15) * 8;
#pragma unroll
  for (int c = 0; c < 4; ++c) {
    uint4 u;
    u.x = (unsigned int)f2bf(o[c*8+0] * inv) | ((unsigned int)f2bf(o[c*8+1] * inv) << 16);
    u.y = (unsigned int)f2bf(o[c*8+2] * inv) | ((unsigned int)f2bf(o[c*8+3] * inv) << 16);
    u.z = (unsigned int)f2bf(o[c*8+4] * inv) | ((unsigned int)f2bf(o[c*8+5] * inv) << 16);
    u.w = (unsigned int)f2bf(o[c*8+6] * inv) | ((unsigned int)f2bf(o[c*8+7] * inv) << 16);
    *(uint4*)(op + c * 128) = u;
  }
}

// ---------------- launch ----------------
extern "C" void kernel_launch(void* const* d_in, const int* in_sizes, int n_in,
                              void* d_out, int out_size, void* d_ws, size_t ws_size,
                              hipStream_t stream) {
  const float* x     = (const float*)d_in[0];
  const float* Wqkv  = (const float*)d_in[1];
  const float* bqkv  = (const float*)d_in[2];
  const float* Wproj = (const float*)d_in[3];
  const float* bproj = (const float*)d_in[4];
  float* out = (float*)d_out;

  char* ws = (char*)d_ws;
  unsigned short* x_swz     = (unsigned short*)(ws);                // 25,165,824 B
  unsigned short* attn_swz  = (unsigned short*)(ws + 25165824);     // 25,165,824 B
  unsigned short* wqkv_swz  = (unsigned short*)(ws + 50331648);     //    884,736 B
  unsigned short* wproj_swz = (unsigned short*)(ws + 51216384);     //    294,912 B

  // convert all three fp32 tensors into swizzled fragment-major bf16 (one launch)
  cvt_all<<<6432, 256, 0, stream>>>(x, Wqkv, Wproj, x_swz, wqkv_swz, wproj_swz);

  // fused qkv-projection + dilated attention (qkv never hits HBM)
  fused_qkv_attn<<<dim3(ROWS / 64, 3), 256, 0, stream>>>(x_swz, wqkv_swz, bqkv, attn_swz);

  // out = attn @ Wproj^T + bproj  (fp32 row-major out); col-tiles dispatch-fastest
  gemm_swz<0, DIM, DIM><<<dim3(DIM / 128, ROWS / 128), 256, 0, stream>>>(
      attn_swz, wproj_swz, bproj, (void*)out);
}